// Round 2
// baseline (1681.470 us; speedup 1.0000x reference)
//
#include <hip/hip_runtime.h>
#include <stdint.h>

typedef unsigned short u16;
typedef _Float16 half_t;
typedef __attribute__((ext_vector_type(4))) float f32x4;
typedef __attribute__((ext_vector_type(8))) _Float16 f16x8;

#define NS_A 3.4445f
#define NS_B -4.7750f
#define NS_C 2.0315f

// scales (exact powers of 2, folded into epilogues):
//   x stored as 64*x ; a stored as 4096*a ; bmat stored as 4096*bmat
#define SX      64.0f
#define INV_SX  (1.0f / 64.0f)
#define INV_SA  (1.0f / 4096.0f)

// ---- async global->LDS, 16B per lane (wave-uniform LDS base + lane*16 implicit)
typedef const __attribute__((address_space(1))) void* as1_cvp;
typedef __attribute__((address_space(3))) void* as3_vp;
#define GLOAD_LDS16(gp, lp) \
    __builtin_amdgcn_global_load_lds((as1_cvp)(const void*)(gp), (as3_vp)(void*)(lp), 16, 0, 0)

// =======================================================================
// NT GEMM: C[i,j] = sum_k A[i,k] * B[j,k]   (A: MxK row-major, B: NxK row-major)
// 128x128 tile, BK=32, 256 threads (4 waves, 2x2 of 64x64 quadrants),
// global_load_lds width 16, 16x16x32 f16 MFMA, fp32 accum.
// MODE 0: out_f16 = acc                          (a_s = x_s x_s^T, scale 4096)
// MODE 1: out_f16 = NS_B*aux + NS_C*acc/4096     (bmat_s; acc = a_s@a_s, aux = a_s)
// MODE 2: out_f16 = NS_A*aux + acc/4096          (x'_s;  acc = bmat_s@x_s^T^T, aux = x_s)
// MODE 3: out_f32 = acc/64 + bias[col]           (final; acc = x @ (64*w_orth)^T)
// =======================================================================
#define BM 128
#define BN 128
#define BK 32

template <int MODE>
__global__ __launch_bounds__(256) void gemm_nt(
    const half_t* __restrict__ A, const half_t* __restrict__ B,
    const half_t* __restrict__ aux, const float* __restrict__ bias,
    void* __restrict__ outp, int M, int N, int K)
{
    __shared__ half_t As[BM * BK];
    __shared__ half_t Bs[BN * BK];
    const int tid  = threadIdx.x;
    const int wave = tid >> 6;
    const int lane = tid & 63;
    const int nbx  = N / BN;
    const int brow = (blockIdx.x / nbx) * BM;
    const int bcol = (blockIdx.x % nbx) * BN;
    const int wr = wave >> 1, wc = wave & 1;

    f32x4 acc[4][4] = {};

    const int r0 = tid >> 2;           // chunk row within 64-row half
    const int c8 = (tid & 3) * 8;      // 8-element column offset

    for (int kt = 0; kt < K; kt += BK) {
#pragma unroll
        for (int j = 0; j < 2; ++j) {
            const int row = j * 64 + r0;
            const half_t* gpa = A + (size_t)(brow + row) * K + kt + c8;
            const half_t* gpb = B + (size_t)(bcol + row) * K + kt + c8;
            half_t* lpa = &As[(size_t)(j * 256 + wave * 64) * 8];
            half_t* lpb = &Bs[(size_t)(j * 256 + wave * 64) * 8];
            GLOAD_LDS16(gpa, lpa);
            GLOAD_LDS16(gpb, lpb);
        }
        __syncthreads();

        f16x8 af[4], bfr[4];
#pragma unroll
        for (int m = 0; m < 4; ++m)
            af[m] = *(const f16x8*)&As[(wr * 64 + m * 16 + (lane & 15)) * BK + (lane >> 4) * 8];
#pragma unroll
        for (int n = 0; n < 4; ++n)
            bfr[n] = *(const f16x8*)&Bs[(wc * 64 + n * 16 + (lane & 15)) * BK + (lane >> 4) * 8];
#pragma unroll
        for (int m = 0; m < 4; ++m)
#pragma unroll
            for (int n = 0; n < 4; ++n)
                acc[m][n] = __builtin_amdgcn_mfma_f32_16x16x32_f16(af[m], bfr[n], acc[m][n], 0, 0, 0);
        __syncthreads();
    }

    // epilogue: C/D layout col = lane&15, row = (lane>>4)*4 + r
#pragma unroll
    for (int m = 0; m < 4; ++m) {
#pragma unroll
        for (int n = 0; n < 4; ++n) {
            const int row0 = brow + wr * 64 + m * 16 + (lane >> 4) * 4;
            const int col  = bcol + wc * 64 + n * 16 + (lane & 15);
#pragma unroll
            for (int r = 0; r < 4; ++r) {
                const size_t idx = (size_t)(row0 + r) * N + col;
                const float v = acc[m][n][r];
                if (MODE == 0) {
                    ((half_t*)outp)[idx] = (half_t)v;
                } else if (MODE == 1) {
                    ((half_t*)outp)[idx] = (half_t)(NS_B * (float)aux[idx] + NS_C * v * INV_SA);
                } else if (MODE == 2) {
                    ((half_t*)outp)[idx] = (half_t)(NS_A * (float)aux[idx] + v * INV_SA);
                } else {
                    ((float*)outp)[idx] = v * INV_SX + bias[col];
                }
            }
        }
    }
}

// ---- deterministic Frobenius-norm reduction (fixed order, no float atomics)
__global__ __launch_bounds__(256) void k_sumsq(const float* __restrict__ w,
                                               float* __restrict__ part, int n) {
    __shared__ float s[256];
    const int per  = n / 1024;
    const int base = blockIdx.x * per;
    float acc = 0.f;
    for (int i = threadIdx.x; i < per; i += 256) {
        float v = w[base + i];
        acc += v * v;
    }
    s[threadIdx.x] = acc;
    __syncthreads();
    for (int k = 128; k > 0; k >>= 1) {
        if (threadIdx.x < k) s[threadIdx.x] += s[threadIdx.x + k];
        __syncthreads();
    }
    if (threadIdx.x == 0) part[blockIdx.x] = s[0];
}

__global__ __launch_bounds__(256) void k_scalefin(const float* __restrict__ part,
                                                  float* __restrict__ scale) {
    __shared__ float s[256];
    float acc = 0.f;
    for (int i = threadIdx.x; i < 1024; i += 256) acc += part[i];
    s[threadIdx.x] = acc;
    __syncthreads();
    for (int k = 128; k > 0; k >>= 1) {
        if (threadIdx.x < k) s[threadIdx.x] += s[threadIdx.x + k];
        __syncthreads();
    }
    if (threadIdx.x == 0) scale[0] = SX / (sqrtf(s[0]) + 1e-7f);
}

// ---- x0_s = w * (64/(|w|+eps)) -> f16
__global__ __launch_bounds__(256) void k_scale_f16(const float* __restrict__ w,
                                                   const float* __restrict__ scale,
                                                   half_t* __restrict__ o, int n) {
    const int i = (blockIdx.x * 256 + threadIdx.x) * 4;
    if (i < n) {
        const float sc = scale[0];
        float4 v = *(const float4*)(w + i);
        o[i + 0] = (half_t)(v.x * sc);
        o[i + 1] = (half_t)(v.y * sc);
        o[i + 2] = (half_t)(v.z * sc);
        o[i + 3] = (half_t)(v.w * sc);
    }
}

// ---- f32 -> f16 cast (unscaled; |x| <= ~6 fits f16 fine)
__global__ __launch_bounds__(256) void k_cast_f16(const float* __restrict__ w,
                                                  half_t* __restrict__ o, int n) {
    const int i = (blockIdx.x * 256 + threadIdx.x) * 4;
    if (i < n) {
        float4 v = *(const float4*)(w + i);
        o[i + 0] = (half_t)v.x;
        o[i + 1] = (half_t)v.y;
        o[i + 2] = (half_t)v.z;
        o[i + 3] = (half_t)v.w;
    }
}

// ---- 16-bit NxN transpose, 64x64 LDS tiles (+1 pad)
__global__ __launch_bounds__(256) void k_transpose(const u16* __restrict__ in,
                                                   u16* __restrict__ out, int n) {
    __shared__ u16 tile[64][65];
    const int bx = blockIdx.x * 64, by = blockIdx.y * 64;
    const int tx = threadIdx.x & 63, ty = threadIdx.x >> 6;
    for (int i = ty; i < 64; i += 4) tile[i][tx] = in[(size_t)(by + i) * n + bx + tx];
    __syncthreads();
    for (int i = ty; i < 64; i += 4) out[(size_t)(bx + i) * n + by + tx] = tile[tx][i];
}

extern "C" void kernel_launch(void* const* d_in, const int* in_sizes, int n_in,
                              void* d_out, int out_size, void* d_ws, size_t ws_size,
                              hipStream_t stream) {
    const float* x = (const float*)d_in[0];
    const float* w = (const float*)d_in[1];
    const float* b = (const float*)d_in[2];
    float* out = (float*)d_out;

    const int D  = 2048;
    const int Bm = in_sizes[0] / D;      // 16384
    const int WN = D * D;
    const int XN = Bm * D;

    char* ws = (char*)d_ws;
    float* part  = (float*)ws;
    float* scale = part + 1024;
    half_t* xb0  = (half_t*)(ws + 8192);
    half_t* xb1  = xb0 + WN;
    half_t* xbT  = xb1 + WN;
    half_t* amat = xbT + WN;
    half_t* bmat = amat + WN;
    half_t* xinb = bmat + WN;

    // 1. frobenius norm -> scale; x0_s = 64*w/(|w|+eps) in f16
    k_sumsq<<<1024, 256, 0, stream>>>(w, part, WN);
    k_scalefin<<<1, 256, 0, stream>>>(part, scale);
    k_scale_f16<<<WN / 4 / 256, 256, 0, stream>>>(w, scale, xb0, WN);

    // 2. x -> f16 (final GEMM operand)
    k_cast_f16<<<XN / 4 / 256, 256, 0, stream>>>(x, xinb, XN);

    const dim3 tgrid(D / 64, D / 64);
    const int ns_grid = (D / BM) * (D / BN);

    // 3. Newton-Schulz iterations (scaled f16)
    half_t* cur = xb0;
    half_t* nxt = xb1;
    for (int it = 0; it < 10; ++it) {
        k_transpose<<<tgrid, 256, 0, stream>>>((const u16*)cur, (u16*)xbT, D);
        gemm_nt<0><<<ns_grid, 256, 0, stream>>>(cur, cur, nullptr, nullptr, amat, D, D, D);
        gemm_nt<1><<<ns_grid, 256, 0, stream>>>(amat, amat, amat, nullptr, bmat, D, D, D);
        gemm_nt<2><<<ns_grid, 256, 0, stream>>>(bmat, xbT, cur, nullptr, nxt, D, D, D);
        half_t* t = cur; cur = nxt; nxt = t;
    }

    // 4. out = x @ w_orth + b
    k_transpose<<<tgrid, 256, 0, stream>>>((const u16*)cur, (u16*)xbT, D);
    const int fin_grid = (Bm / BM) * (D / BN);
    gemm_nt<3><<<fin_grid, 256, 0, stream>>>(xinb, xbT, nullptr, b, out, Bm, D, D);
}

// Round 3
// 1613.828 us; speedup vs baseline: 1.0419x; 1.0419x over previous
//
#include <hip/hip_runtime.h>
#include <stdint.h>

typedef unsigned short u16;
typedef _Float16 half_t;
typedef __attribute__((ext_vector_type(4))) float f32x4;
typedef __attribute__((ext_vector_type(8))) _Float16 f16x8;

#define NS_A 3.4445f
#define NS_B -4.7750f
#define NS_C 2.0315f

// scales (exact powers of 2, folded into epilogues):
//   x stored as 64*x ; a stored as 4096*a ; bmat stored as 4096*bmat
#define SX      64.0f
#define INV_SX  (1.0f / 64.0f)
#define INV_SA  (1.0f / 4096.0f)

// ---- async global->LDS, 16B per lane (wave-uniform LDS base + lane*16 implicit)
typedef const __attribute__((address_space(1))) void* as1_cvp;
typedef __attribute__((address_space(3))) void* as3_vp;
#define GLOAD_LDS16(gp, lp) \
    __builtin_amdgcn_global_load_lds((as1_cvp)(const void*)(gp), (as3_vp)(void*)(lp), 16, 0, 0)

// =======================================================================
// NT GEMM: C[i,j] = sum_k A[i,k] * B[j,k]   (A: MxK row-major, B: NxK row-major)
// 128x128 tile, BK=64 (32 KB LDS), 256 threads (4 waves, 2x2 of 64x64),
// global_load_lds width 16, 16x16x32 f16 MFMA, fp32 accum.
// MODE 0: out_f16 = acc                          (a_s = x_s x_s^T)
// MODE 1: out_f16 = NS_B*aux + NS_C*acc/4096     (bmat_s; acc = a_s@a_s, aux = a_s)
// MODE 2: out_f16 = NS_A*aux + acc/4096          (x'_s;  acc = bmat_s @ x_s, aux = x_s)
// MODE 3: out_f32 = acc/64 + bias[col]           (final)
// SWZ: XCD-aware bijective blockIdx remap (gridDim.x % 8 == 0 required)
// =======================================================================
#define BM 128
#define BN 128
#define BK 64

template <int MODE, bool SWZ>
__global__ __launch_bounds__(256) void gemm_nt(
    const half_t* __restrict__ A, const half_t* __restrict__ B,
    const half_t* __restrict__ aux, const float* __restrict__ bias,
    void* __restrict__ outp, int M, int N, int K)
{
    __shared__ half_t As[BM * BK];
    __shared__ half_t Bs[BN * BK];
    const int tid  = threadIdx.x;
    const int wave = tid >> 6;
    const int lane = tid & 63;

    int bid = blockIdx.x;
    if (SWZ) {
        const int cpx = gridDim.x >> 3;      // chunk per XCD
        bid = (bid & 7) * cpx + (bid >> 3);  // XCD i gets a contiguous tile chunk
    }
    const int nbx  = N / BN;
    const int brow = (bid / nbx) * BM;
    const int bcol = (bid % nbx) * BN;
    const int wr = wave >> 1, wc = wave & 1;

    f32x4 acc[4][4] = {};

    // staging geometry: 1024 chunks of 16B (8 f16), 8 chunks per row.
    // chunk = j*256 + tid -> row = chunk>>3, col8 = (chunk&7)*8
    const int r0 = tid >> 3;           // + j*32
    const int c8 = (tid & 7) * 8;

    for (int kt = 0; kt < K; kt += BK) {
#pragma unroll
        for (int j = 0; j < 4; ++j) {
            const int row = j * 32 + r0;
            const half_t* gpa = A + (size_t)(brow + row) * K + kt + c8;
            const half_t* gpb = B + (size_t)(bcol + row) * K + kt + c8;
            // wave-uniform LDS chunk base: j*256 + wave*64 (lane*16B implicit)
            half_t* lpa = &As[(size_t)(j * 256 + wave * 64) * 8];
            half_t* lpb = &Bs[(size_t)(j * 256 + wave * 64) * 8];
            GLOAD_LDS16(gpa, lpa);
            GLOAD_LDS16(gpb, lpb);
        }
        __syncthreads();

        f16x8 af[4][2], bfr[4][2];
#pragma unroll
        for (int m = 0; m < 4; ++m)
#pragma unroll
            for (int kk = 0; kk < 2; ++kk)
                af[m][kk] = *(const f16x8*)&As[(wr * 64 + m * 16 + (lane & 15)) * BK + kk * 32 + (lane >> 4) * 8];
#pragma unroll
        for (int n = 0; n < 4; ++n)
#pragma unroll
            for (int kk = 0; kk < 2; ++kk)
                bfr[n][kk] = *(const f16x8*)&Bs[(wc * 64 + n * 16 + (lane & 15)) * BK + kk * 32 + (lane >> 4) * 8];
#pragma unroll
        for (int kk = 0; kk < 2; ++kk)
#pragma unroll
            for (int m = 0; m < 4; ++m)
#pragma unroll
                for (int n = 0; n < 4; ++n)
                    acc[m][n] = __builtin_amdgcn_mfma_f32_16x16x32_f16(af[m][kk], bfr[n][kk], acc[m][n], 0, 0, 0);
        __syncthreads();
    }

    // epilogue: C/D layout col = lane&15, row = (lane>>4)*4 + r
#pragma unroll
    for (int m = 0; m < 4; ++m) {
#pragma unroll
        for (int n = 0; n < 4; ++n) {
            const int row0 = brow + wr * 64 + m * 16 + (lane >> 4) * 4;
            const int col  = bcol + wc * 64 + n * 16 + (lane & 15);
#pragma unroll
            for (int r = 0; r < 4; ++r) {
                const size_t idx = (size_t)(row0 + r) * N + col;
                const float v = acc[m][n][r];
                if (MODE == 0) {
                    ((half_t*)outp)[idx] = (half_t)v;
                } else if (MODE == 1) {
                    ((half_t*)outp)[idx] = (half_t)(NS_B * (float)aux[idx] + NS_C * v * INV_SA);
                } else if (MODE == 2) {
                    ((half_t*)outp)[idx] = (half_t)(NS_A * (float)aux[idx] + v * INV_SA);
                } else {
                    ((float*)outp)[idx] = v * INV_SX + bias[col];
                }
            }
        }
    }
}

// ---- deterministic Frobenius-norm reduction (fixed order, no float atomics)
__global__ __launch_bounds__(256) void k_sumsq(const float* __restrict__ w,
                                               float* __restrict__ part, int n) {
    __shared__ float s[256];
    const int per  = n / 1024;
    const int base = blockIdx.x * per;
    float acc = 0.f;
    for (int i = threadIdx.x; i < per; i += 256) {
        float v = w[base + i];
        acc += v * v;
    }
    s[threadIdx.x] = acc;
    __syncthreads();
    for (int k = 128; k > 0; k >>= 1) {
        if (threadIdx.x < k) s[threadIdx.x] += s[threadIdx.x + k];
        __syncthreads();
    }
    if (threadIdx.x == 0) part[blockIdx.x] = s[0];
}

__global__ __launch_bounds__(256) void k_scalefin(const float* __restrict__ part,
                                                  float* __restrict__ scale) {
    __shared__ float s[256];
    float acc = 0.f;
    for (int i = threadIdx.x; i < 1024; i += 256) acc += part[i];
    s[threadIdx.x] = acc;
    __syncthreads();
    for (int k = 128; k > 0; k >>= 1) {
        if (threadIdx.x < k) s[threadIdx.x] += s[threadIdx.x + k];
        __syncthreads();
    }
    if (threadIdx.x == 0) scale[0] = SX / (sqrtf(s[0]) + 1e-7f);
}

// ---- x0_s = w * (64/(|w|+eps)) -> f16
__global__ __launch_bounds__(256) void k_scale_f16(const float* __restrict__ w,
                                                   const float* __restrict__ scale,
                                                   half_t* __restrict__ o, int n) {
    const int i = (blockIdx.x * 256 + threadIdx.x) * 4;
    if (i < n) {
        const float sc = scale[0];
        float4 v = *(const float4*)(w + i);
        o[i + 0] = (half_t)(v.x * sc);
        o[i + 1] = (half_t)(v.y * sc);
        o[i + 2] = (half_t)(v.z * sc);
        o[i + 3] = (half_t)(v.w * sc);
    }
}

// ---- f32 -> f16 cast
__global__ __launch_bounds__(256) void k_cast_f16(const float* __restrict__ w,
                                                  half_t* __restrict__ o, int n) {
    const int i = (blockIdx.x * 256 + threadIdx.x) * 4;
    if (i < n) {
        float4 v = *(const float4*)(w + i);
        o[i + 0] = (half_t)v.x;
        o[i + 1] = (half_t)v.y;
        o[i + 2] = (half_t)v.z;
        o[i + 3] = (half_t)v.w;
    }
}

// ---- 16-bit NxN transpose, 64x64 LDS tiles (+1 pad)
__global__ __launch_bounds__(256) void k_transpose(const u16* __restrict__ in,
                                                   u16* __restrict__ out, int n) {
    __shared__ u16 tile[64][65];
    const int bx = blockIdx.x * 64, by = blockIdx.y * 64;
    const int tx = threadIdx.x & 63, ty = threadIdx.x >> 6;
    for (int i = ty; i < 64; i += 4) tile[i][tx] = in[(size_t)(by + i) * n + bx + tx];
    __syncthreads();
    for (int i = ty; i < 64; i += 4) out[(size_t)(bx + i) * n + by + tx] = tile[tx][i];
}

extern "C" void kernel_launch(void* const* d_in, const int* in_sizes, int n_in,
                              void* d_out, int out_size, void* d_ws, size_t ws_size,
                              hipStream_t stream) {
    const float* x = (const float*)d_in[0];
    const float* w = (const float*)d_in[1];
    const float* b = (const float*)d_in[2];
    float* out = (float*)d_out;

    const int D  = 2048;
    const int Bm = in_sizes[0] / D;      // 16384
    const int WN = D * D;
    const int XN = Bm * D;

    char* ws = (char*)d_ws;
    float* part  = (float*)ws;
    float* scale = part + 1024;
    half_t* xb0  = (half_t*)(ws + 8192);
    half_t* xb1  = xb0 + WN;
    half_t* xbT  = xb1 + WN;
    half_t* amat = xbT + WN;
    half_t* bmat = amat + WN;
    half_t* xinb = bmat + WN;

    // 1. frobenius norm -> scale; x0_s = 64*w/(|w|+eps) in f16
    k_sumsq<<<1024, 256, 0, stream>>>(w, part, WN);
    k_scalefin<<<1, 256, 0, stream>>>(part, scale);
    k_scale_f16<<<WN / 4 / 256, 256, 0, stream>>>(w, scale, xb0, WN);

    // 2. x -> f16 (final GEMM operand)
    k_cast_f16<<<XN / 4 / 256, 256, 0, stream>>>(x, xinb, XN);

    const dim3 tgrid(D / 64, D / 64);
    const int ns_grid = (D / BM) * (D / BN);      // 256

    // 3. Newton-Schulz iterations (scaled f16)
    half_t* cur = xb0;
    half_t* nxt = xb1;
    for (int it = 0; it < 10; ++it) {
        k_transpose<<<tgrid, 256, 0, stream>>>((const u16*)cur, (u16*)xbT, D);
        gemm_nt<0, false><<<ns_grid, 256, 0, stream>>>(cur, cur, nullptr, nullptr, amat, D, D, D);
        gemm_nt<1, false><<<ns_grid, 256, 0, stream>>>(amat, amat, amat, nullptr, bmat, D, D, D);
        gemm_nt<2, false><<<ns_grid, 256, 0, stream>>>(bmat, xbT, cur, nullptr, nxt, D, D, D);
        half_t* t = cur; cur = nxt; nxt = t;
    }

    // 4. out = x @ w_orth + b   (XCD-swizzled: 2048 blocks, %8==0)
    k_transpose<<<tgrid, 256, 0, stream>>>((const u16*)cur, (u16*)xbT, D);
    const int fin_grid = (Bm / BM) * (D / BN);    // 2048
    gemm_nt<3, true><<<fin_grid, 256, 0, stream>>>(xinb, xbT, nullptr, b, out, Bm, D, D);
}

// Round 4
// 1254.726 us; speedup vs baseline: 1.3401x; 1.2862x over previous
//
#include <hip/hip_runtime.h>
#include <stdint.h>

typedef unsigned short u16;
typedef _Float16 half_t;
typedef __attribute__((ext_vector_type(4))) float f32x4;
typedef __attribute__((ext_vector_type(8))) _Float16 f16x8;

#define NS_A 3.4445f
#define NS_B -4.7750f
#define NS_C 2.0315f

// scales (exact powers of 2, folded into epilogues):
//   x stored as 64*x ; a stored as 4096*a ; bmat stored as 4096*bmat
#define SX      64.0f
#define INV_SX  (1.0f / 64.0f)
#define INV_SA  (1.0f / 4096.0f)

// ---- async global->LDS, 16B per lane (wave-uniform LDS base + lane*16 implicit)
typedef const __attribute__((address_space(1))) void* as1_cvp;
typedef __attribute__((address_space(3))) void* as3_vp;
#define GLOAD_LDS16(gp, lp) \
    __builtin_amdgcn_global_load_lds((as1_cvp)(const void*)(gp), (as3_vp)(void*)(lp), 16, 0, 0)

// =======================================================================
// NT GEMM: C[i,j] = sum_k A[i,k] * B[j,k]   (A: MxK row-major, B: NxK row-major)
// 128x128 tile, BK=64, double-buffered LDS (64 KB), 256 threads (4 waves),
// T3-minimum 2-phase pipeline: STAGE(next) issued before ds_read+MFMA(cur),
// one vmcnt-drain barrier per K-step.
// LDS XOR swizzle (rule #21): linear gload_lds dest + pre-swizzled global
// source column-chunk (chunk ^= row&7) + identical XOR on ds_read address.
// MODE 0: out_f16 = acc                          (a_s = x_s x_s^T)
// MODE 1: out_f16 = NS_B*aux + NS_C*acc/4096     (bmat_s; acc = a_s@a_s)
// MODE 2: out_f16 = NS_A*aux + acc/4096          (x'_s; also writes outT)
// MODE 3: out_f32 = acc/64 + bias[col]           (final)
// SWZ: XCD-aware blockIdx remap (gridDim.x % 8 == 0 required)
// =======================================================================
#define BM 128
#define BN 128
#define BK 64

template <int MODE, bool SWZ>
__global__ __launch_bounds__(256, 2) void gemm_nt(
    const half_t* __restrict__ A, const half_t* __restrict__ B,
    const half_t* __restrict__ aux, const float* __restrict__ bias,
    void* __restrict__ outp, half_t* __restrict__ outpT,
    int M, int N, int K)
{
    __shared__ half_t As[2][BM * BK];
    __shared__ half_t Bs[2][BN * BK];
    const int tid  = threadIdx.x;
    const int wave = tid >> 6;
    const int lane = tid & 63;

    int bid = blockIdx.x;
    if (SWZ) {
        const int cpx = gridDim.x >> 3;
        bid = (bid & 7) * cpx + (bid >> 3);
    }
    const int nbx  = N / BN;
    const int brow = (bid / nbx) * BM;
    const int bcol = (bid % nbx) * BN;
    const int wr = wave >> 1, wc = wave & 1;

    f32x4 acc[4][4] = {};

    // staging: 1024 chunks of 16B per matrix. chunk c = j*256 + tid
    //   -> LDS row = j*32 + (tid>>3), LDS chunk-col = tid&7
    //   holds global column-chunk (tid&7) ^ (row&7)   [row&7 == (tid>>3)&7]
    const int r0  = tid >> 3;
    const int c8s = (((tid & 7) ^ ((tid >> 3) & 7))) * 8;

    const half_t* gA = A + (size_t)(brow + r0) * K + c8s;
    const half_t* gB = B + (size_t)(bcol + r0) * K + c8s;

    auto stage = [&](int buf, int kt) {
#pragma unroll
        for (int j = 0; j < 4; ++j) {
            GLOAD_LDS16(gA + (size_t)(j * 32) * K + kt, &As[buf][(size_t)(j * 256 + wave * 64) * 8]);
            GLOAD_LDS16(gB + (size_t)(j * 32) * K + kt, &Bs[buf][(size_t)(j * 256 + wave * 64) * 8]);
        }
    };

    stage(0, 0);
    __syncthreads();   // drains vmcnt(0): buf0 landed

    const int nsteps = K / BK;
    for (int s = 0; s < nsteps; ++s) {
        const int cur = s & 1;
        if (s + 1 < nsteps) stage(cur ^ 1, (s + 1) * BK);  // prefetch under compute

        f16x8 af[4][2], bfr[4][2];
#pragma unroll
        for (int m = 0; m < 4; ++m) {
            const int row = wr * 64 + m * 16 + (lane & 15);
#pragma unroll
            for (int kk = 0; kk < 2; ++kk) {
                const int cc = (kk * 4 + (lane >> 4)) ^ (row & 7);
                af[m][kk] = *(const f16x8*)&As[cur][row * BK + cc * 8];
            }
        }
#pragma unroll
        for (int n = 0; n < 4; ++n) {
            const int row = wc * 64 + n * 16 + (lane & 15);
#pragma unroll
            for (int kk = 0; kk < 2; ++kk) {
                const int cc = (kk * 4 + (lane >> 4)) ^ (row & 7);
                bfr[n][kk] = *(const f16x8*)&Bs[cur][row * BK + cc * 8];
            }
        }
#pragma unroll
        for (int kk = 0; kk < 2; ++kk)
#pragma unroll
            for (int m = 0; m < 4; ++m)
#pragma unroll
                for (int n = 0; n < 4; ++n)
                    acc[m][n] = __builtin_amdgcn_mfma_f32_16x16x32_f16(af[m][kk], bfr[n][kk], acc[m][n], 0, 0, 0);

        __syncthreads();   // drains vmcnt(0) (prefetch landed) + lgkm; next step reads buf^1
    }

    // epilogue: C/D layout col = lane&15, row = (lane>>4)*4 + r
#pragma unroll
    for (int m = 0; m < 4; ++m) {
#pragma unroll
        for (int n = 0; n < 4; ++n) {
            const int row0 = brow + wr * 64 + m * 16 + (lane >> 4) * 4;
            const int col  = bcol + wc * 64 + n * 16 + (lane & 15);
#pragma unroll
            for (int r = 0; r < 4; ++r) {
                const size_t idx = (size_t)(row0 + r) * N + col;
                const float v = acc[m][n][r];
                if (MODE == 0) {
                    ((half_t*)outp)[idx] = (half_t)v;
                } else if (MODE == 1) {
                    ((half_t*)outp)[idx] = (half_t)(NS_B * (float)aux[idx] + NS_C * v * INV_SA);
                } else if (MODE == 2) {
                    const half_t o = (half_t)(NS_A * (float)aux[idx] + v * INV_SA);
                    ((half_t*)outp)[idx] = o;
                    outpT[(size_t)col * M + row0 + r] = o;  // fused transpose write
                } else {
                    ((float*)outp)[idx] = v * INV_SX + bias[col];
                }
            }
        }
    }
}

// ---- deterministic Frobenius-norm reduction (fixed order, no float atomics)
__global__ __launch_bounds__(256) void k_sumsq(const float* __restrict__ w,
                                               float* __restrict__ part, int n) {
    __shared__ float s[256];
    const int per  = n / 1024;
    const int base = blockIdx.x * per;
    float acc = 0.f;
    for (int i = threadIdx.x; i < per; i += 256) {
        float v = w[base + i];
        acc += v * v;
    }
    s[threadIdx.x] = acc;
    __syncthreads();
    for (int k = 128; k > 0; k >>= 1) {
        if (threadIdx.x < k) s[threadIdx.x] += s[threadIdx.x + k];
        __syncthreads();
    }
    if (threadIdx.x == 0) part[blockIdx.x] = s[0];
}

__global__ __launch_bounds__(256) void k_scalefin(const float* __restrict__ part,
                                                  float* __restrict__ scale) {
    __shared__ float s[256];
    float acc = 0.f;
    for (int i = threadIdx.x; i < 1024; i += 256) acc += part[i];
    s[threadIdx.x] = acc;
    __syncthreads();
    for (int k = 128; k > 0; k >>= 1) {
        if (threadIdx.x < k) s[threadIdx.x] += s[threadIdx.x + k];
        __syncthreads();
    }
    if (threadIdx.x == 0) scale[0] = SX / (sqrtf(s[0]) + 1e-7f);
}

// ---- x0_s = w * (64/(|w|+eps)) -> f16
__global__ __launch_bounds__(256) void k_scale_f16(const float* __restrict__ w,
                                                   const float* __restrict__ scale,
                                                   half_t* __restrict__ o, int n) {
    const int i = (blockIdx.x * 256 + threadIdx.x) * 4;
    if (i < n) {
        const float sc = scale[0];
        float4 v = *(const float4*)(w + i);
        o[i + 0] = (half_t)(v.x * sc);
        o[i + 1] = (half_t)(v.y * sc);
        o[i + 2] = (half_t)(v.z * sc);
        o[i + 3] = (half_t)(v.w * sc);
    }
}

// ---- f32 -> f16 cast
__global__ __launch_bounds__(256) void k_cast_f16(const float* __restrict__ w,
                                                  half_t* __restrict__ o, int n) {
    const int i = (blockIdx.x * 256 + threadIdx.x) * 4;
    if (i < n) {
        float4 v = *(const float4*)(w + i);
        o[i + 0] = (half_t)v.x;
        o[i + 1] = (half_t)v.y;
        o[i + 2] = (half_t)v.z;
        o[i + 3] = (half_t)v.w;
    }
}

// ---- 16-bit NxN transpose, 64x64 LDS tiles (+1 pad) — used once for x0
__global__ __launch_bounds__(256) void k_transpose(const u16* __restrict__ in,
                                                   u16* __restrict__ out, int n) {
    __shared__ u16 tile[64][65];
    const int bx = blockIdx.x * 64, by = blockIdx.y * 64;
    const int tx = threadIdx.x & 63, ty = threadIdx.x >> 6;
    for (int i = ty; i < 64; i += 4) tile[i][tx] = in[(size_t)(by + i) * n + bx + tx];
    __syncthreads();
    for (int i = ty; i < 64; i += 4) out[(size_t)(bx + i) * n + by + tx] = tile[tx][i];
}

extern "C" void kernel_launch(void* const* d_in, const int* in_sizes, int n_in,
                              void* d_out, int out_size, void* d_ws, size_t ws_size,
                              hipStream_t stream) {
    const float* x = (const float*)d_in[0];
    const float* w = (const float*)d_in[1];
    const float* b = (const float*)d_in[2];
    float* out = (float*)d_out;

    const int D  = 2048;
    const int Bm = in_sizes[0] / D;      // 16384
    const int WN = D * D;
    const int XN = Bm * D;

    char* ws = (char*)d_ws;
    float* part  = (float*)ws;
    float* scale = part + 1024;
    half_t* xb0  = (half_t*)(ws + 8192);
    half_t* xb1  = xb0 + WN;
    half_t* xbT  = xb1 + WN;
    half_t* amat = xbT + WN;
    half_t* bmat = amat + WN;
    half_t* xinb = bmat + WN;

    // 1. frobenius norm -> scale; x0_s = 64*w/(|w|+eps) in f16
    k_sumsq<<<1024, 256, 0, stream>>>(w, part, WN);
    k_scalefin<<<1, 256, 0, stream>>>(part, scale);
    k_scale_f16<<<WN / 4 / 256, 256, 0, stream>>>(w, scale, xb0, WN);

    // 2. x -> f16 (final GEMM operand)
    k_cast_f16<<<XN / 4 / 256, 256, 0, stream>>>(x, xinb, XN);

    // 3. x0^T (only standalone transpose; later iterations get it fused)
    const dim3 tgrid(D / 64, D / 64);
    k_transpose<<<tgrid, 256, 0, stream>>>((const u16*)xb0, (u16*)xbT, D);

    const int ns_grid = (D / BM) * (D / BN);      // 256

    // 4. Newton-Schulz iterations (scaled f16)
    half_t* cur = xb0;
    half_t* nxt = xb1;
    for (int it = 0; it < 10; ++it) {
        gemm_nt<0, false><<<ns_grid, 256, 0, stream>>>(cur, cur, nullptr, nullptr, amat, nullptr, D, D, D);
        gemm_nt<1, false><<<ns_grid, 256, 0, stream>>>(amat, amat, amat, nullptr, bmat, nullptr, D, D, D);
        // x' = NS_A*x + bmat@x ; writes x' and x'^T (xbT, consumed next iter + final)
        gemm_nt<2, false><<<ns_grid, 256, 0, stream>>>(bmat, xbT, cur, nullptr, nxt, xbT, D, D, D);
        half_t* t = cur; cur = nxt; nxt = t;
    }

    // 5. out = x @ w_orth + b   (w_orth^T = xbT from the last iteration)
    const int fin_grid = (Bm / BM) * (D / BN);    // 2048
    gemm_nt<3, true><<<fin_grid, 256, 0, stream>>>(xinb, xbT, nullptr, b, out, nullptr, Bm, D, D);
}

// Round 5
// 1123.533 us; speedup vs baseline: 1.4966x; 1.1168x over previous
//
#include <hip/hip_runtime.h>
#include <stdint.h>

typedef unsigned short u16;
typedef _Float16 half_t;
typedef __attribute__((ext_vector_type(4))) float f32x4;
typedef __attribute__((ext_vector_type(8))) _Float16 f16x8;

#define NS_A 3.4445f
#define NS_B -4.7750f
#define NS_C 2.0315f

// scales (exact powers of 2, folded into epilogues):
//   x stored as 64*x ; a stored as 4096*a ; bmat stored as 4096*bmat
#define SX      64.0f
#define INV_SX  (1.0f / 64.0f)
#define INV_SA  (1.0f / 4096.0f)

// ---- async global->LDS, 16B per lane (wave-uniform LDS base + lane*16 implicit)
typedef const __attribute__((address_space(1))) void* as1_cvp;
typedef __attribute__((address_space(3))) void* as3_vp;
#define GLOAD_LDS16(gp, lp) \
    __builtin_amdgcn_global_load_lds((as1_cvp)(const void*)(gp), (as3_vp)(void*)(lp), 16, 0, 0)

// =======================================================================
// NT GEMM: C[i,j] = sum_k A[i,k] * B[j,k]   (A: MxK row-major, B: NxK row-major)
// BMt x BNt tile, BK=64, double-buffered LDS, 256 threads (4 waves, 2x2),
// 2-phase pipeline: STAGE(next) issued before ds_read+MFMA(cur),
// one vmcnt-drain barrier per K-step.
// LDS XOR swizzle (both-sides): linear gload_lds dest + pre-swizzled global
// source column-chunk (chunk ^= row&7) + identical XOR on ds_read address.
// MODE 0: out_f16 = acc                          (a_s = x_s x_s^T)
// MODE 1: out_f16 = NS_B*aux + NS_C*acc/4096     (bmat_s; acc = a_s@a_s)
// MODE 2: out_f16 = NS_A*aux + acc/4096          (x'_s; optional fused outT)
// MODE 3: out_f32 = acc/64 + bias[col]           (final)
// SWZ: XCD-aware blockIdx remap (gridDim.x % 8 == 0 required)
// NS GEMMs use 64x128 (grid 512 = 2 blocks/CU for TLP); final uses 128x128.
// =======================================================================
#define BK 64

template <int MODE, bool SWZ, int BMt, int BNt>
__global__ __launch_bounds__(256, 3) void gemm_nt(
    const half_t* __restrict__ A, const half_t* __restrict__ B,
    const half_t* __restrict__ aux, const float* __restrict__ bias,
    void* __restrict__ outp, half_t* __restrict__ outpT,
    int M, int N, int K)
{
    constexpr int M_REP = BMt / 32;   // fragment repeats per wave (rows)
    constexpr int N_REP = BNt / 32;   // fragment repeats per wave (cols)

    __shared__ half_t As[2][BMt * BK];
    __shared__ half_t Bs[2][BNt * BK];
    const int tid  = threadIdx.x;
    const int wave = tid >> 6;
    const int lane = tid & 63;

    int bid = blockIdx.x;
    if (SWZ) {
        const int cpx = gridDim.x >> 3;
        bid = (bid & 7) * cpx + (bid >> 3);
    }
    const int nbx  = N / BNt;
    const int brow = (bid / nbx) * BMt;
    const int bcol = (bid % nbx) * BNt;
    const int wr = wave >> 1, wc = wave & 1;

    f32x4 acc[M_REP][N_REP] = {};

    // staging: chunks of 16B (8 f16), 8 chunks per row (BK=64).
    // chunk c = j*256 + tid -> row = j*32 + (tid>>3), chunk-col = tid&7
    // global source column-chunk pre-swizzled: ^ (row&7)
    const int r0  = tid >> 3;
    const int c8s = (((tid & 7) ^ ((tid >> 3) & 7))) * 8;

    const half_t* gA = A + (size_t)(brow + r0) * K + c8s;
    const half_t* gB = B + (size_t)(bcol + r0) * K + c8s;

    auto stage = [&](int buf, int kt) {
#pragma unroll
        for (int j = 0; j < BMt / 32; ++j)
            GLOAD_LDS16(gA + (size_t)(j * 32) * K + kt, &As[buf][(size_t)(j * 256 + wave * 64) * 8]);
#pragma unroll
        for (int j = 0; j < BNt / 32; ++j)
            GLOAD_LDS16(gB + (size_t)(j * 32) * K + kt, &Bs[buf][(size_t)(j * 256 + wave * 64) * 8]);
    };

    stage(0, 0);
    __syncthreads();   // drains vmcnt(0): buf0 landed

    const int nsteps = K / BK;
    for (int s = 0; s < nsteps; ++s) {
        const int cur = s & 1;
        if (s + 1 < nsteps) stage(cur ^ 1, (s + 1) * BK);  // prefetch under compute

        f16x8 af[M_REP][2], bfr[N_REP][2];
#pragma unroll
        for (int m = 0; m < M_REP; ++m) {
            const int row = wr * (BMt / 2) + m * 16 + (lane & 15);
#pragma unroll
            for (int kk = 0; kk < 2; ++kk) {
                const int cc = (kk * 4 + (lane >> 4)) ^ (row & 7);
                af[m][kk] = *(const f16x8*)&As[cur][row * BK + cc * 8];
            }
        }
#pragma unroll
        for (int n = 0; n < N_REP; ++n) {
            const int row = wc * (BNt / 2) + n * 16 + (lane & 15);
#pragma unroll
            for (int kk = 0; kk < 2; ++kk) {
                const int cc = (kk * 4 + (lane >> 4)) ^ (row & 7);
                bfr[n][kk] = *(const f16x8*)&Bs[cur][row * BK + cc * 8];
            }
        }
#pragma unroll
        for (int kk = 0; kk < 2; ++kk)
#pragma unroll
            for (int m = 0; m < M_REP; ++m)
#pragma unroll
                for (int n = 0; n < N_REP; ++n)
                    acc[m][n] = __builtin_amdgcn_mfma_f32_16x16x32_f16(af[m][kk], bfr[n][kk], acc[m][n], 0, 0, 0);

        __syncthreads();   // drains vmcnt(0) (prefetch landed) + lgkm
    }

    // epilogue: C/D layout col = lane&15, row = (lane>>4)*4 + r
#pragma unroll
    for (int m = 0; m < M_REP; ++m) {
#pragma unroll
        for (int n = 0; n < N_REP; ++n) {
            const int row0 = brow + wr * (BMt / 2) + m * 16 + (lane >> 4) * 4;
            const int col  = bcol + wc * (BNt / 2) + n * 16 + (lane & 15);
#pragma unroll
            for (int r = 0; r < 4; ++r) {
                const size_t idx = (size_t)(row0 + r) * N + col;
                const float v = acc[m][n][r];
                if (MODE == 0) {
                    ((half_t*)outp)[idx] = (half_t)v;
                } else if (MODE == 1) {
                    ((half_t*)outp)[idx] = (half_t)(NS_B * (float)aux[idx] + NS_C * v * INV_SA);
                } else if (MODE == 2) {
                    const half_t o = (half_t)(NS_A * (float)aux[idx] + v * INV_SA);
                    ((half_t*)outp)[idx] = o;
                    if (outpT) outpT[(size_t)col * M + row0 + r] = o;  // fused transpose
                } else {
                    ((float*)outp)[idx] = v * INV_SX + bias[col];
                }
            }
        }
    }
}

// ---- deterministic Frobenius-norm reduction (fixed order, no float atomics)
__global__ __launch_bounds__(256) void k_sumsq(const float* __restrict__ w,
                                               float* __restrict__ part, int n) {
    __shared__ float s[256];
    const int per  = n / 1024;
    const int base = blockIdx.x * per;
    float acc = 0.f;
    for (int i = threadIdx.x; i < per; i += 256) {
        float v = w[base + i];
        acc += v * v;
    }
    s[threadIdx.x] = acc;
    __syncthreads();
    for (int k = 128; k > 0; k >>= 1) {
        if (threadIdx.x < k) s[threadIdx.x] += s[threadIdx.x + k];
        __syncthreads();
    }
    if (threadIdx.x == 0) part[blockIdx.x] = s[0];
}

__global__ __launch_bounds__(256) void k_scalefin(const float* __restrict__ part,
                                                  float* __restrict__ scale) {
    __shared__ float s[256];
    float acc = 0.f;
    for (int i = threadIdx.x; i < 1024; i += 256) acc += part[i];
    s[threadIdx.x] = acc;
    __syncthreads();
    for (int k = 128; k > 0; k >>= 1) {
        if (threadIdx.x < k) s[threadIdx.x] += s[threadIdx.x + k];
        __syncthreads();
    }
    if (threadIdx.x == 0) scale[0] = SX / (sqrtf(s[0]) + 1e-7f);
}

// ---- x0_s = w * (64/(|w|+eps)) -> f16
__global__ __launch_bounds__(256) void k_scale_f16(const float* __restrict__ w,
                                                   const float* __restrict__ scale,
                                                   half_t* __restrict__ o, int n) {
    const int i = (blockIdx.x * 256 + threadIdx.x) * 4;
    if (i < n) {
        const float sc = scale[0];
        float4 v = *(const float4*)(w + i);
        o[i + 0] = (half_t)(v.x * sc);
        o[i + 1] = (half_t)(v.y * sc);
        o[i + 2] = (half_t)(v.z * sc);
        o[i + 3] = (half_t)(v.w * sc);
    }
}

// ---- f32 -> f16 cast
__global__ __launch_bounds__(256) void k_cast_f16(const float* __restrict__ w,
                                                  half_t* __restrict__ o, int n) {
    const int i = (blockIdx.x * 256 + threadIdx.x) * 4;
    if (i < n) {
        float4 v = *(const float4*)(w + i);
        o[i + 0] = (half_t)v.x;
        o[i + 1] = (half_t)v.y;
        o[i + 2] = (half_t)v.z;
        o[i + 3] = (half_t)v.w;
    }
}

// ---- 16-bit NxN transpose, 64x64 LDS tiles (+1 pad)
__global__ __launch_bounds__(256) void k_transpose(const u16* __restrict__ in,
                                                   u16* __restrict__ out, int n) {
    __shared__ u16 tile[64][65];
    const int bx = blockIdx.x * 64, by = blockIdx.y * 64;
    const int tx = threadIdx.x & 63, ty = threadIdx.x >> 6;
    for (int i = ty; i < 64; i += 4) tile[i][tx] = in[(size_t)(by + i) * n + bx + tx];
    __syncthreads();
    for (int i = ty; i < 64; i += 4) out[(size_t)(bx + i) * n + by + tx] = tile[tx][i];
}

extern "C" void kernel_launch(void* const* d_in, const int* in_sizes, int n_in,
                              void* d_out, int out_size, void* d_ws, size_t ws_size,
                              hipStream_t stream) {
    const float* x = (const float*)d_in[0];
    const float* w = (const float*)d_in[1];
    const float* b = (const float*)d_in[2];
    float* out = (float*)d_out;

    const int D  = 2048;
    const int Bm = in_sizes[0] / D;      // 16384
    const int WN = D * D;
    const int XN = Bm * D;

    // ws layout: part/scale | xb0 xb1 xbTa [xbTb] amat bmat | xinb
    // ping-pong transpose needs one extra 8MB buffer; guard on ws_size.
    const size_t matB = (size_t)WN * 2;
    const bool pingpong = ws_size >= 8192 + 6 * matB + (size_t)XN * 2;

    char* ws = (char*)d_ws;
    float* part  = (float*)ws;
    float* scale = part + 1024;
    half_t* xb0  = (half_t*)(ws + 8192);
    half_t* xb1  = xb0 + WN;
    half_t* xbTa = xb1 + WN;
    half_t* xbTb = pingpong ? (xbTa + WN) : xbTa;   // alias if ws too small
    half_t* amat = xbTb + WN;                        // (xbTb==xbTa shifts layout ok)
    half_t* bmat = amat + WN;
    half_t* xinb = bmat + WN;

    // 1. frobenius norm -> scale; x0_s = 64*w/(|w|+eps) in f16
    k_sumsq<<<1024, 256, 0, stream>>>(w, part, WN);
    k_scalefin<<<1, 256, 0, stream>>>(part, scale);
    k_scale_f16<<<WN / 4 / 256, 256, 0, stream>>>(w, scale, xb0, WN);

    // 2. x -> f16 (final GEMM operand)
    k_cast_f16<<<XN / 4 / 256, 256, 0, stream>>>(x, xinb, XN);

    // 3. x0^T
    const dim3 tgrid(D / 64, D / 64);
    k_transpose<<<tgrid, 256, 0, stream>>>((const u16*)xb0, (u16*)xbTa, D);

    const int ns_grid = (D / 64) * (D / 128);      // 512 blocks = 2/CU

    // 4. Newton-Schulz iterations (scaled f16), 64x128 tiles
    half_t* cur = xb0;
    half_t* nxt = xb1;
    half_t* Tr  = xbTa;   // holds cur^T
    half_t* Tw  = xbTb;   // receives nxt^T
    for (int it = 0; it < 10; ++it) {
        gemm_nt<0, true, 64, 128><<<ns_grid, 256, 0, stream>>>(cur, cur, nullptr, nullptr, amat, nullptr, D, D, D);
        gemm_nt<1, true, 64, 128><<<ns_grid, 256, 0, stream>>>(amat, amat, amat, nullptr, bmat, nullptr, D, D, D);
        if (pingpong) {
            // x' = NS_A*x + bmat@x ; fused x'^T write into the OTHER buffer (race-free)
            gemm_nt<2, true, 64, 128><<<ns_grid, 256, 0, stream>>>(bmat, Tr, cur, nullptr, nxt, Tw, D, D, D);
            half_t* tt = Tr; Tr = Tw; Tw = tt;
        } else {
            gemm_nt<2, true, 64, 128><<<ns_grid, 256, 0, stream>>>(bmat, Tr, cur, nullptr, nxt, nullptr, D, D, D);
            k_transpose<<<tgrid, 256, 0, stream>>>((const u16*)nxt, (u16*)Tr, D);
        }
        half_t* t = cur; cur = nxt; nxt = t;
    }

    // 5. out = x @ w_orth + b   (w_orth^T = Tr)
    const int fin_grid = (Bm / 128) * (D / 128);    // 2048
    gemm_nt<3, true, 128, 128><<<fin_grid, 256, 0, stream>>>(xinb, Tr, nullptr, b, out, nullptr, Bm, D, D);
}